// Round 1
// baseline (124.863 us; speedup 1.0000x reference)
//
#include <hip/hip_runtime.h>
#include <hip/hip_bf16.h>
#include <cstdint>

// GAT fused layer: B=4, N=2048, F=128, H=8, HD=16, all fp32 I/O.
// Kernel 1 (proj): XW = x@W (fp32), emit WxT bf16 [B][128][N], e_i/e_j fp32
//                  pre-scaled by log2(e), plus WoT = Wo^T for coalesced loads.
// Kernel 2 (gat): per (b, 16-row tile): 8 waves (one head each), barrier-free
//                 j-loop: scores in registers laid out as MFMA A-frags,
//                 aggregation via mfma_f32_16x16x32_bf16, fused out-proj+ELU.

typedef float f32x4 __attribute__((ext_vector_type(4)));
typedef __bf16 bf16x8 __attribute__((ext_vector_type(8)));

#define LOG2E 1.44269504088896340736f

#if __has_builtin(__builtin_amdgcn_exp2f)
#define EXP2F(x) __builtin_amdgcn_exp2f(x)
#else
#define EXP2F(x) __expf((x) * 0.69314718055994531f)
#endif

__global__ __launch_bounds__(128)
void proj_kernel(const float* __restrict__ x, const float* __restrict__ W,
                 const float* __restrict__ a, const float* __restrict__ Wo,
                 unsigned short* __restrict__ wxT, float* __restrict__ ei,
                 float* __restrict__ ej, float* __restrict__ WoT)
{
    const int t = threadIdx.x;
    const int blk = blockIdx.x;
    if (blk == 1024) {
        // WoT[k][f] = Wo[f][k]
        for (int k = 0; k < 128; ++k)
            WoT[k * 128 + t] = Wo[t * 128 + k];
        return;
    }
    __shared__ float xl[8 * 128];
    __shared__ float xw[8 * 128];
    const int row0 = blk * 8;  // global row in [0, 8192)
    #pragma unroll
    for (int r = 0; r < 8; ++r)
        xl[r * 128 + t] = x[(size_t)(row0 + r) * 128 + t];
    __syncthreads();

    float acc[8] = {0.f, 0.f, 0.f, 0.f, 0.f, 0.f, 0.f, 0.f};
    for (int k = 0; k < 128; k += 4) {
        const float w0 = W[(k + 0) * 128 + t];
        const float w1 = W[(k + 1) * 128 + t];
        const float w2 = W[(k + 2) * 128 + t];
        const float w3 = W[(k + 3) * 128 + t];
        #pragma unroll
        for (int r = 0; r < 8; ++r) {
            const float4 xv = *reinterpret_cast<const float4*>(&xl[r * 128 + k]);
            acc[r] += xv.x * w0 + xv.y * w1 + xv.z * w2 + xv.w * w3;
        }
    }
    #pragma unroll
    for (int r = 0; r < 8; ++r) xw[r * 128 + t] = acc[r];
    __syncthreads();

    const int b = row0 >> 11, n0 = row0 & 2047;

    // WxT bf16: [B][128 f][2048 n]; thread t owns feature f=t, 8 consecutive n.
    bf16x8 st;
    #pragma unroll
    for (int r = 0; r < 8; ++r) st[r] = (__bf16)xw[r * 128 + t];
    *reinterpret_cast<bf16x8*>(&wxT[((size_t)(b * 128 + t)) * 2048 + n0]) = st;

    // e_i / e_j: 8 rows x 8 heads x 2 = 128 dot products of length 16.
    const int r = t >> 4, h = (t >> 1) & 7, s = t & 1;
    float dot = 0.f;
    #pragma unroll
    for (int d = 0; d < 16; ++d)
        dot += xw[r * 128 + h * 16 + d] * a[h * 32 + s * 16 + d];
    float* dst = s ? ej : ei;
    dst[(b * 8 + h) * 2048 + n0 + r] = dot * LOG2E;  // pre-scale for exp2
}

__global__ __launch_bounds__(512)
void gat_kernel(const int* __restrict__ adj, const unsigned short* __restrict__ wxT,
                const float* __restrict__ ei, const float* __restrict__ ej,
                const float* __restrict__ WoT, const float* __restrict__ bo,
                float* __restrict__ out)
{
    const int tid = threadIdx.x;
    const int h = tid >> 6;          // wave = head
    const int lane = tid & 63;
    const int r = lane & 15;         // A-frag row / B-frag col
    const int jg = lane >> 4;        // j-octet group
    const int b = blockIdx.x >> 7;
    const int ibase = (blockIdx.x & 127) << 4;

    __shared__ float hl[16 * 128];

    const float eiv = ei[(b * 8 + h) * 2048 + ibase + r];
    const int* adjrow = adj + ((size_t)(b * 2048 + ibase + r)) * 2048;
    const float* ejrow = ej + (b * 8 + h) * 2048;
    const unsigned short* vrow = wxT + ((size_t)(b * 128 + h * 16 + r)) * 2048;

    f32x4 acc = {0.f, 0.f, 0.f, 0.f};
    float lsum = 0.f;

    for (int jt = 0; jt < 2048; jt += 64) {
        #pragma unroll
        for (int kk = 0; kk < 2; ++kk) {
            const int j0 = jt + kk * 32 + jg * 8;
            const int4 a0 = *reinterpret_cast<const int4*>(&adjrow[j0]);
            const int4 a1 = *reinterpret_cast<const int4*>(&adjrow[j0 + 4]);
            const float4 e0 = *reinterpret_cast<const float4*>(&ejrow[j0]);
            const float4 e1 = *reinterpret_cast<const float4*>(&ejrow[j0 + 4]);
            const bf16x8 bfr = *reinterpret_cast<const bf16x8*>(&vrow[j0]);
            const float ee[8] = {e0.x, e0.y, e0.z, e0.w, e1.x, e1.y, e1.z, e1.w};
            const int   aa[8] = {a0.x, a0.y, a0.z, a0.w, a1.x, a1.y, a1.z, a1.w};
            float p[8];
            #pragma unroll
            for (int e2 = 0; e2 < 8; ++e2) {
                float z = eiv + ee[e2];        // log2-domain logit
                z = fmaxf(z, 0.2f * z);        // leaky_relu (scale-invariant)
                const float pe = EXP2F(z);     // no max-subtraction needed: |z| <= ~6
                p[e2] = aa[e2] ? pe : 0.f;
                lsum += p[e2];
            }
            bf16x8 afr;
            #pragma unroll
            for (int e2 = 0; e2 < 8; ++e2) afr[e2] = (__bf16)p[e2];
            acc = __builtin_amdgcn_mfma_f32_16x16x32_bf16(afr, bfr, acc, 0, 0, 0);
        }
    }

    // full row-sum: lanes {r, r+16, r+32, r+48} hold disjoint j-subsets of row r
    lsum += __shfl_xor(lsum, 16);
    lsum += __shfl_xor(lsum, 32);

    // C/D layout: col = lane&15, row = (lane>>4)*4 + q
    #pragma unroll
    for (int q = 0; q < 4; ++q) {
        const int row = jg * 4 + q;
        const float ls = __shfl(lsum, row);   // lane 'row' (<16) holds row's sum
        const float inv = (ls > 0.f) ? 1.f / ls : 0.f;  // empty row -> 0 (nan_to_num)
        hl[row * 128 + h * 16 + r] = acc[q] * inv;
    }
    __syncthreads();

    // fused out-proj + ELU: out[n,f] = elu(sum_k h[n,k]*Wo[f,k] + bo[f])
    const int f = tid & 127;
    const int rg = tid >> 7;  // 4 row-groups x 4 rows
    float o0 = 0.f, o1 = 0.f, o2 = 0.f, o3 = 0.f;
    for (int k = 0; k < 128; k += 4) {
        const float w0 = WoT[(k + 0) * 128 + f];
        const float w1 = WoT[(k + 1) * 128 + f];
        const float w2 = WoT[(k + 2) * 128 + f];
        const float w3 = WoT[(k + 3) * 128 + f];
        const float4 h0 = *reinterpret_cast<const float4*>(&hl[(rg * 4 + 0) * 128 + k]);
        const float4 h1 = *reinterpret_cast<const float4*>(&hl[(rg * 4 + 1) * 128 + k]);
        const float4 h2 = *reinterpret_cast<const float4*>(&hl[(rg * 4 + 2) * 128 + k]);
        const float4 h3 = *reinterpret_cast<const float4*>(&hl[(rg * 4 + 3) * 128 + k]);
        o0 += h0.x * w0 + h0.y * w1 + h0.z * w2 + h0.w * w3;
        o1 += h1.x * w0 + h1.y * w1 + h1.z * w2 + h1.w * w3;
        o2 += h2.x * w0 + h2.y * w1 + h2.z * w2 + h2.w * w3;
        o3 += h3.x * w0 + h3.y * w1 + h3.z * w2 + h3.w * w3;
    }
    const float bv = bo[f];
    float vv[4] = {o0 + bv, o1 + bv, o2 + bv, o3 + bv};
    #pragma unroll
    for (int q = 0; q < 4; ++q) {
        float v = vv[q];
        v = (v > 0.f) ? v : (__expf(v) - 1.f);
        out[(size_t)(b * 2048 + ibase + rg * 4 + q) * 128 + f] = v;
    }
}

extern "C" void kernel_launch(void* const* d_in, const int* in_sizes, int n_in,
                              void* d_out, int out_size, void* d_ws, size_t ws_size,
                              hipStream_t stream) {
    const float* x   = (const float*)d_in[0];
    const int*   adj = (const int*)d_in[1];
    const float* W   = (const float*)d_in[2];
    const float* a   = (const float*)d_in[3];
    const float* Wo  = (const float*)d_in[4];
    const float* bo  = (const float*)d_in[5];
    float* out = (float*)d_out;

    // ws layout: WxT bf16 (2 MB) | ei (256 KB) | ej (256 KB) | WoT (64 KB)
    char* ws = (char*)d_ws;
    unsigned short* wxT = (unsigned short*)ws;
    float* ei  = (float*)(ws + (size_t)4 * 128 * 2048 * 2);
    float* ej  = ei + 4 * 8 * 2048;
    float* WoT = ej + 4 * 8 * 2048;

    proj_kernel<<<dim3(1025), dim3(128), 0, stream>>>(x, W, a, Wo, wxT, ei, ej, WoT);
    gat_kernel<<<dim3(512), dim3(512), 0, stream>>>(adj, wxT, ei, ej, WoT, bo, out);
}

// Round 2
// 89.737 us; speedup vs baseline: 1.3914x; 1.3914x over previous
//
#include <hip/hip_runtime.h>
#include <hip/hip_bf16.h>
#include <cstdint>

// GAT fused layer: B=4, N=2048, F=128, H=8, HD=16, all fp32 I/O.
// proj: XW = x@W (fp32), emit WxT bf16 [B][128][N], e_i/e_j fp32 (pre-scaled
//       by log2 e), plus WoT = Wo^T.
// gat:  per (b, 16-row tile): phase 1 packs the tile's 16 adj rows into LDS
//       bitmasks (coalesced, read once); phase 2: 8 waves (one head each),
//       barrier-free j-loop with scores in registers as MFMA A-frags,
//       aggregation AND row-sum via mfma_f32_16x16x32_bf16 (B=ones trick),
//       fused out-proj + ELU.

typedef float f32x4 __attribute__((ext_vector_type(4)));
typedef __bf16 bf16x8 __attribute__((ext_vector_type(8)));

#define LOG2E 1.44269504088896340736f

#if __has_builtin(__builtin_amdgcn_exp2f)
#define EXP2F(x) __builtin_amdgcn_exp2f(x)
#else
#define EXP2F(x) __expf((x) * 0.69314718055994531f)
#endif

__global__ __launch_bounds__(128)
void proj_kernel(const float* __restrict__ x, const float* __restrict__ W,
                 const float* __restrict__ a, const float* __restrict__ Wo,
                 unsigned short* __restrict__ wxT, float* __restrict__ ei,
                 float* __restrict__ ej, float* __restrict__ WoT)
{
    const int t = threadIdx.x;
    const int blk = blockIdx.x;
    if (blk == 1024) {
        for (int k = 0; k < 128; ++k)
            WoT[k * 128 + t] = Wo[t * 128 + k];
        return;
    }
    __shared__ float xl[8 * 128];
    __shared__ float xw[8 * 128];
    const int row0 = blk * 8;
    #pragma unroll
    for (int r = 0; r < 8; ++r)
        xl[r * 128 + t] = x[(size_t)(row0 + r) * 128 + t];
    __syncthreads();

    float acc[8] = {0.f, 0.f, 0.f, 0.f, 0.f, 0.f, 0.f, 0.f};
    for (int k = 0; k < 128; k += 4) {
        const float w0 = W[(k + 0) * 128 + t];
        const float w1 = W[(k + 1) * 128 + t];
        const float w2 = W[(k + 2) * 128 + t];
        const float w3 = W[(k + 3) * 128 + t];
        #pragma unroll
        for (int r = 0; r < 8; ++r) {
            const float4 xv = *reinterpret_cast<const float4*>(&xl[r * 128 + k]);
            acc[r] += xv.x * w0 + xv.y * w1 + xv.z * w2 + xv.w * w3;
        }
    }
    #pragma unroll
    for (int r = 0; r < 8; ++r) xw[r * 128 + t] = acc[r];
    __syncthreads();

    const int b = row0 >> 11, n0 = row0 & 2047;

    bf16x8 st;
    #pragma unroll
    for (int r = 0; r < 8; ++r) st[r] = (__bf16)xw[r * 128 + t];
    *reinterpret_cast<bf16x8*>(&wxT[((size_t)(b * 128 + t)) * 2048 + n0]) = st;

    const int r = t >> 4, h = (t >> 1) & 7, s = t & 1;
    float dot = 0.f;
    #pragma unroll
    for (int d = 0; d < 16; ++d)
        dot += xw[r * 128 + h * 16 + d] * a[h * 32 + s * 16 + d];
    float* dst = s ? ej : ei;
    dst[(b * 8 + h) * 2048 + n0 + r] = dot * LOG2E;
}

__global__ __launch_bounds__(512)
void gat_kernel(const int* __restrict__ adj, const unsigned short* __restrict__ wxT,
                const float* __restrict__ ei, const float* __restrict__ ej,
                const float* __restrict__ WoT, const float* __restrict__ bo,
                float* __restrict__ out)
{
    const int tid = threadIdx.x;
    const int h = tid >> 6;          // wave = head
    const int lane = tid & 63;
    const int r = lane & 15;         // A-frag row / B-frag col
    const int jg = lane >> 4;        // j-octet group
    const int b = blockIdx.x >> 7;
    const int ibase = (blockIdx.x & 127) << 4;

    __shared__ unsigned long long lbits[16][33];  // stride 33 -> conflict-free
    __shared__ float hl[16 * 128];

    // ---- Phase 1: pack this tile's 16 adj rows into bitmasks (read once, coalesced)
    {
        const int w = h;  // wave id 0..7, handles rows 2w, 2w+1
        #pragma unroll
        for (int rr2 = 0; rr2 < 2; ++rr2) {
            const int rr = w * 2 + rr2;
            const int* arow = adj + ((size_t)(b * 2048 + ibase + rr)) * 2048;
            for (int it = 0; it < 32; ++it) {
                const unsigned long long m = __ballot(arow[it * 64 + lane] != 0);
                if (lane == 0) lbits[rr][it] = m;
            }
        }
    }
    __syncthreads();

    // ---- Phase 2: attention j-loop
    const float eiv = ei[(b * 8 + h) * 2048 + ibase + r];
    const float* ejrow = ej + (b * 8 + h) * 2048;
    const unsigned short* vrow = wxT + ((size_t)(b * 128 + h * 16 + r)) * 2048;

    f32x4 acc  = {0.f, 0.f, 0.f, 0.f};
    f32x4 accS = {0.f, 0.f, 0.f, 0.f};
    bf16x8 ones;
    #pragma unroll
    for (int e2 = 0; e2 < 8; ++e2) ones[e2] = (__bf16)1.0f;

    for (int jt = 0; jt < 2048; jt += 64) {
        const unsigned long long bl = lbits[r][jt >> 6] >> (jg * 8);
        const unsigned int m01[2] = {(unsigned int)bl, (unsigned int)(bl >> 32)};
        #pragma unroll
        for (int kk = 0; kk < 2; ++kk) {
            const int j0 = jt + kk * 32 + jg * 8;
            const float4 e0 = *reinterpret_cast<const float4*>(&ejrow[j0]);
            const float4 e1 = *reinterpret_cast<const float4*>(&ejrow[j0 + 4]);
            const bf16x8 bfr = *reinterpret_cast<const bf16x8*>(&vrow[j0]);
            const unsigned int mk = m01[kk];
            const float ee[8] = {e0.x, e0.y, e0.z, e0.w, e1.x, e1.y, e1.z, e1.w};
            bf16x8 afr;
            #pragma unroll
            for (int e2 = 0; e2 < 8; ++e2) {
                float z = eiv + ee[e2];         // log2-domain logit
                z = fmaxf(z, 0.2f * z);         // leaky_relu
                const float pe = EXP2F(z);      // |z| small: no max-subtract needed
                afr[e2] = (__bf16)(((mk >> e2) & 1u) ? pe : 0.f);
            }
            acc  = __builtin_amdgcn_mfma_f32_16x16x32_bf16(afr, bfr,  acc,  0, 0, 0);
            accS = __builtin_amdgcn_mfma_f32_16x16x32_bf16(afr, ones, accS, 0, 0, 0);
        }
    }

    // C/D layout: col = lane&15, row = (lane>>4)*4 + q. accS[q] = row sum (any col).
    #pragma unroll
    for (int q = 0; q < 4; ++q) {
        const int row = jg * 4 + q;
        const float ls = accS[q];
        const float inv = (ls > 0.f) ? 1.f / ls : 0.f;  // empty row -> 0 (nan_to_num)
        hl[row * 128 + h * 16 + r] = acc[q] * inv;
    }
    __syncthreads();

    // ---- fused out-proj + ELU
    const int f = tid & 127;
    const int rg = tid >> 7;
    float o0 = 0.f, o1 = 0.f, o2 = 0.f, o3 = 0.f;
    for (int k = 0; k < 128; k += 4) {
        const float w0 = WoT[(k + 0) * 128 + f];
        const float w1 = WoT[(k + 1) * 128 + f];
        const float w2 = WoT[(k + 2) * 128 + f];
        const float w3 = WoT[(k + 3) * 128 + f];
        const float4 h0 = *reinterpret_cast<const float4*>(&hl[(rg * 4 + 0) * 128 + k]);
        const float4 h1 = *reinterpret_cast<const float4*>(&hl[(rg * 4 + 1) * 128 + k]);
        const float4 h2 = *reinterpret_cast<const float4*>(&hl[(rg * 4 + 2) * 128 + k]);
        const float4 h3 = *reinterpret_cast<const float4*>(&hl[(rg * 4 + 3) * 128 + k]);
        o0 += h0.x * w0 + h0.y * w1 + h0.z * w2 + h0.w * w3;
        o1 += h1.x * w0 + h1.y * w1 + h1.z * w2 + h1.w * w3;
        o2 += h2.x * w0 + h2.y * w1 + h2.z * w2 + h2.w * w3;
        o3 += h3.x * w0 + h3.y * w1 + h3.z * w2 + h3.w * w3;
    }
    const float bv = bo[f];
    float vv[4] = {o0 + bv, o1 + bv, o2 + bv, o3 + bv};
    #pragma unroll
    for (int q = 0; q < 4; ++q) {
        float v = vv[q];
        v = (v > 0.f) ? v : (__expf(v) - 1.f);
        out[(size_t)(b * 2048 + ibase + rg * 4 + q) * 128 + f] = v;
    }
}

extern "C" void kernel_launch(void* const* d_in, const int* in_sizes, int n_in,
                              void* d_out, int out_size, void* d_ws, size_t ws_size,
                              hipStream_t stream) {
    const float* x   = (const float*)d_in[0];
    const int*   adj = (const int*)d_in[1];
    const float* W   = (const float*)d_in[2];
    const float* a   = (const float*)d_in[3];
    const float* Wo  = (const float*)d_in[4];
    const float* bo  = (const float*)d_in[5];
    float* out = (float*)d_out;

    char* ws = (char*)d_ws;
    unsigned short* wxT = (unsigned short*)ws;
    float* ei  = (float*)(ws + (size_t)4 * 128 * 2048 * 2);
    float* ej  = ei + 4 * 8 * 2048;
    float* WoT = ej + 4 * 8 * 2048;

    proj_kernel<<<dim3(1025), dim3(128), 0, stream>>>(x, W, a, Wo, wxT, ei, ej, WoT);
    gat_kernel<<<dim3(512), dim3(512), 0, stream>>>(adj, wxT, ei, ej, WoT, bo, out);
}